// Round 1
// baseline (289.287 us; speedup 1.0000x reference)
//
#include <hip/hip_runtime.h>

// MHA forward, B=2, S=2048, D=1024, H=16, Dk=64, causal, RoPE. fp32 I/O.
// Internal bf16 MFMA 16x16x32, fp32 accum.
// R11: QKV epilogue was trig-bound; RoPE cos/sin precomputed into a 2048x32
// float2 table by a tiny kernel; GEMM epilogue does one 8B load instead.
// R12: attn was grid-limited to 2 blocks/CU (Occupancy 16%, MfmaUtil 9%,
// HBM 3.6% -- pure latency-bound). Un-paired the q-tiles: one q-tile per
// block -> 1024 blocks = 4 blocks/CU (VGPR<=128, LDS 18.4KB both allow it).
// Same total work (procs/syncs/staging identical); static complementary
// (i, 31-i) slot interleave keeps per-CU load balanced at ~66 procs.

typedef unsigned short u16;
typedef __attribute__((ext_vector_type(8))) short short8;   // 8 bf16 = 4 VGPRs
typedef __attribute__((ext_vector_type(4))) float float4v;  // MFMA C/D

typedef const __attribute__((address_space(1))) void GV;    // global
typedef __attribute__((address_space(3))) void LV;          // LDS

#define VSTR 72   // attn Vt/Ps row stride (u16): 144B rows, 2-way read banks
#define QSCL 0.18033688011112042f   // 0.125 * log2(e)

__device__ __forceinline__ u16 f2b(float f) {
    union { float f; unsigned int i; } t; t.f = f;
    unsigned int r = t.i + 0x7fffu + ((t.i >> 16) & 1u);   // RNE
    return (u16)(r >> 16);
}

// ---------------- fused fp32 -> bf16 converter ------------------------------
__global__ __launch_bounds__(256) void cvt_all(
    const float4* __restrict__ x,  const float4* __restrict__ wq,
    const float4* __restrict__ wk, const float4* __restrict__ wv,
    const float4* __restrict__ wo,
    u16* __restrict__ xb, u16* __restrict__ wcat, u16* __restrict__ wob)
{
    const int i = blockIdx.x * 256 + threadIdx.x;
    const float4* s; u16* d; int off;
    if (i < 524288) { s = x; d = xb; off = i; }
    else {
        const int widx = i - 524288;
        const int w = widx >> 17, o = widx & 131071;
        switch (w) {
            case 0:  s = wq; d = wcat;              break;
            case 1:  s = wk; d = wcat + (1 << 20);  break;
            case 2:  s = wv; d = wcat + (2 << 20);  break;
            default: s = wo; d = wob;               break;
        }
        off = o;
    }
    float4 a = s[2 * off], b = s[2 * off + 1];
    u16 t[8] = {f2b(a.x), f2b(a.y), f2b(a.z), f2b(a.w),
                f2b(b.x), f2b(b.y), f2b(b.z), f2b(b.w)};
    reinterpret_cast<int4*>(d)[off] = *reinterpret_cast<int4*>(t);
}

// ---------------- RoPE cos/sin table: tab[pos*32+fi] = {cos, sin} ----------
__global__ __launch_bounds__(256) void rope_tab(float2* __restrict__ tab) {
    const int i = blockIdx.x * 256 + threadIdx.x;   // 0..65535
    const int pos = i >> 5, fi = i & 31;
    const float freq = exp2f((float)fi * -0.4152410118609203f);  // -log2(1e4)/32
    float sn, cs; sincosf((float)pos * freq, &sn, &cs);
    tab[i] = make_float2(cs, sn);
}

// ---------------------------------------------------------------------------
// Y[m][n] = sum_k X[m][k] * W[n][k]; 128(m) x NT*32(n) x 64(k) tiles.
// Staging: global_load_lds width=16. LDS: 64-elem rows, 16B unit u stored at
// phys u^(row&7) (lane-contiguous DMA dest, swizzled ds_read_b128).
// ROPE=1: route cols to Yq/Yk/Yv, RoPE q,k via table, scale q by QSCL.
// XCD swizzle: block g -> xcd=g&7 owns m-strips [xcd*4, xcd*4+4).
// ---------------------------------------------------------------------------
template<int NT, int ROPE, int NBLK>
__global__ __launch_bounds__(256) void gemm_tile(
    const u16* __restrict__ X, const u16* __restrict__ Wb,
    u16* __restrict__ Yq, u16* __restrict__ Yk, u16* __restrict__ Yv,
    float* __restrict__ Yf, const float2* __restrict__ tab)
{
    __shared__ u16 As[128 * 64];
    __shared__ u16 Bs[NT * 32 * 64];

    const int tid  = threadIdx.x;
    const int wave = tid >> 6;
    const int lane = tid & 63;
    const int quad = lane >> 4;
    const int l16  = lane & 15;
    const int wm = (wave >> 1) * 64, wn = (wave & 1) * (NT * 16);
    const int g = blockIdx.x;
    const int rr = g >> 3;
    const int m0 = ((g & 7) * 4 + rr / NBLK) * 128;
    const int n0 = (rr % NBLK) * (NT * 32);
    const int lrow = lane >> 3;                         // 0..7 within 8-row slab
    const int cg8  = (lane & 7) ^ lrow;                 // swizzled global unit

    float4v acc[4][NT];
#pragma unroll
    for (int mt = 0; mt < 4; mt++)
#pragma unroll
        for (int nt = 0; nt < NT; nt++) acc[mt][nt] = (float4v){0.f, 0.f, 0.f, 0.f};

    for (int kb = 0; kb < 1024; kb += 64) {
        __syncthreads();                                 // prev reads done
#pragma unroll
        for (int t = 0; t < 4; t++) {                    // stage A: 4x 1KB/wave
            const int I = wave * 4 + t;
            const u16* gp = X + (size_t)(m0 + I * 8 + lrow) * 1024 + kb + cg8 * 8;
            __builtin_amdgcn_global_load_lds((GV*)gp, (LV*)&As[I * 512], 16, 0, 0);
        }
#pragma unroll
        for (int t = 0; t < NT; t++) {                   // stage B: NTx 1KB/wave
            const int I = wave * NT + t;
            const u16* gp = Wb + (size_t)(n0 + I * 8 + lrow) * 1024 + kb + cg8 * 8;
            __builtin_amdgcn_global_load_lds((GV*)gp, (LV*)&Bs[I * 512], 16, 0, 0);
        }
        __syncthreads();                                 // vmcnt drained here
#pragma unroll
        for (int ks = 0; ks < 2; ks++) {
            const int su = ((ks * 4 + quad) ^ (l16 & 7)) * 8;   // swizzled unit
            short8 af[4], bf[NT];
#pragma unroll
            for (int t = 0; t < 4; t++)
                af[t] = *reinterpret_cast<const short8*>(&As[(wm + t * 16 + l16) * 64 + su]);
#pragma unroll
            for (int t = 0; t < NT; t++)
                bf[t] = *reinterpret_cast<const short8*>(&Bs[(wn + t * 16 + l16) * 64 + su]);
#pragma unroll
            for (int mt = 0; mt < 4; mt++)
#pragma unroll
                for (int nt = 0; nt < NT; nt++)
                    acc[mt][nt] = __builtin_amdgcn_mfma_f32_16x16x32_bf16(af[mt], bf[nt], acc[mt][nt], 0, 0, 0);
        }
    }

    if (ROPE) {
#pragma unroll
        for (int nt = 0; nt < NT; nt++) {
            const int cg = n0 + wn + nt * 16 + l16;      // global col 0..3071
            const int buf = cg >> 10;                    // 0=q 1=k 2=v
            const int c = cg & 1023;
            u16* dst = (buf == 0) ? Yq : ((buf == 1) ? Yk : Yv);
            const bool rp = (buf < 2);
            const float scl = (buf == 0) ? QSCL : 1.0f;
            const int fi = (cg & 63) >> 1;               // pair index in head
#pragma unroll
            for (int mt = 0; mt < 4; mt++)
#pragma unroll
                for (int r = 0; r < 4; r++) {
                    const int row = m0 + wm + mt * 16 + quad * 4 + r;
                    float v = acc[mt][nt][r];
                    if (rp) {
                        const float2 t = tab[((row & 2047) << 5) + fi];
                        const float partner = __shfl_xor(v, 1);
                        v = (l16 & 1) ? fmaf(v, t.x,  partner * t.y)
                                      : fmaf(v, t.x, -partner * t.y);
                    }
                    dst[(size_t)row * 1024 + c] = f2b(v * scl);
                }
        }
    } else {
#pragma unroll
        for (int nt = 0; nt < NT; nt++) {
            const int col = n0 + wn + nt * 16 + l16;
#pragma unroll
            for (int mt = 0; mt < 4; mt++)
#pragma unroll
                for (int r = 0; r < 4; r++) {
                    const int row = m0 + wm + mt * 16 + quad * 4 + r;
                    Yf[(size_t)row * 1024 + col] = acc[mt][nt][r];
                }
        }
    }
}

// ---------------------------------------------------------------------------
// Flash causal attention, ONE 64-row q-tile per block (R12: un-paired ->
// 1024 blocks = 4 blocks/CU). Unnormalized softmax (q pre-scaled
// 0.125*log2e -> p = exp2f(s)). K frags direct from global, prefetched.
// V staged coalesced into XOR-swizzled LDS transpose. XCD grouping: 32
// blocks of one (b,h) share an XCD's L2. Complementary (i, 31-i) slot
// interleave balances per-CU work under round-robin dispatch. O aliases Q.
// ---------------------------------------------------------------------------
__global__ __launch_bounds__(256, 4) void attn_kernel(
    const u16* Q, const u16* __restrict__ K,
    const u16* __restrict__ V, u16* O)
{
    __shared__ u16 Vt[64 * VSTR];           // Vt[d][s^((d>>4)<<4)]
    __shared__ u16 Ps[4 * 16 * VSTR];

    const int tid  = threadIdx.x;
    const int wave = tid >> 6;
    const int lane = tid & 63;
    const int quad = lane >> 4;
    const int l16  = lane & 15;
    const int g = blockIdx.x;
    const int xcd = g & 7, slot = g >> 3;   // slot 0..127 per XCD
    const int grp = slot >> 5;              // 0..3: (b,h) group on this XCD
    const int i5  = slot & 31;
    const int G = grp * 8 + xcd;            // 0..31 = (b,h) group
    const int qt = (grp & 1) ? i5 : 31 - i5;   // complementary interleave
    const int b = G & 1, h = G >> 1;
    const size_t base = ((size_t)b * 2048) * 1024 + (size_t)h * 64;

    short8 qf[2];
    {
        const size_t ra = base + (size_t)(qt * 64 + wave * 16 + l16) * 1024;
        qf[0] = *reinterpret_cast<const short8*>(Q + ra + quad * 8);
        qf[1] = *reinterpret_cast<const short8*>(Q + ra + 32 + quad * 8);
    }

    float4v o[4];
#pragma unroll
    for (int i = 0; i < 4; i++) o[i] = (float4v){0.f,0.f,0.f,0.f};
    float s[4] = {0.f,0.f,0.f,0.f};

    u16* Pw = Ps + wave * 16 * VSTR;
    const int srow = tid >> 2;             // 0..63 (coalesced: 4 lanes/row)
    const int cb   = (tid & 3) << 4;       // 0,16,32,48
    const int sxw  = srow ^ cb;            // swizzled s ((d>>4)<<4 == cb)

    const u16* Vp = V + base + (size_t)srow * 1024 + cb;
    const u16* kbase = K + base + (size_t)l16 * 1024 + quad * 8;
    int4 vr0 = *reinterpret_cast<const int4*>(Vp);
    int4 vr1 = *reinterpret_cast<const int4*>(Vp + 8);
    short8 kn[4][2], kc[4][2], vf[4][2];
#pragma unroll
    for (int nt = 0; nt < 4; nt++)
#pragma unroll
        for (int ks = 0; ks < 2; ks++)
            kn[nt][ks] = *reinterpret_cast<const short8*>(kbase + (size_t)(nt * 16) * 1024 + ks * 32);

    auto proc = [&](bool diag) {
        float4v sacc[4];
#pragma unroll
        for (int nt = 0; nt < 4; nt++) {
            sacc[nt] = (float4v){0.f, 0.f, 0.f, 0.f};
#pragma unroll
            for (int ks = 0; ks < 2; ks++)
                sacc[nt] = __builtin_amdgcn_mfma_f32_16x16x32_bf16(qf[ks], kc[nt][ks], sacc[nt], 0, 0, 0);
        }
#pragma unroll
        for (int r = 0; r < 4; r++) {
            const int qloc = wave * 16 + quad * 4 + r;
#pragma unroll
            for (int nt = 0; nt < 4; nt++) {
                float sv = sacc[nt][r];                      // log2-domain
                if (diag && (nt * 16 + l16 > qloc)) sv = -1e30f;
                const float p = exp2f(sv);                   // masked -> 0
                s[r] += p;
                Pw[(quad * 4 + r) * VSTR + nt * 16 + l16] = f2b(p);
            }
        }
        __builtin_amdgcn_wave_barrier();   // P write->read is wave-local
#pragma unroll
        for (int ks = 0; ks < 2; ks++) {
            short8 pf = *reinterpret_cast<const short8*>(&Pw[l16 * VSTR + ks * 32 + quad * 8]);
#pragma unroll
            for (int dt = 0; dt < 4; dt++)
                o[dt] = __builtin_amdgcn_mfma_f32_16x16x32_bf16(pf, vf[dt][ks], o[dt], 0, 0, 0);
        }
        __builtin_amdgcn_wave_barrier();
    };

    for (int j = 0; j <= qt; j++) {
        __syncthreads();   // all waves done reading previous Vt
        {
            const u16* a = reinterpret_cast<const u16*>(&vr0);   // V[srow][cb..+7]
            const u16* c = reinterpret_cast<const u16*>(&vr1);   // V[srow][cb+8..+15]
#pragma unroll
            for (int e = 0; e < 8; e++) Vt[(cb + e) * VSTR + sxw] = a[e];
#pragma unroll
            for (int e = 0; e < 8; e++) Vt[(cb + 8 + e) * VSTR + sxw] = c[e];
        }
#pragma unroll
        for (int nt = 0; nt < 4; nt++)
#pragma unroll
            for (int ks = 0; ks < 2; ks++) kc[nt][ks] = kn[nt][ks];
        __syncthreads();
        if (j < qt) {      // prefetch tile j+1; latency hidden by proc
            Vp += 65536;
            vr0 = *reinterpret_cast<const int4*>(Vp);
            vr1 = *reinterpret_cast<const int4*>(Vp + 8);
            const u16* kb2 = kbase + (size_t)(j + 1) * 65536;
#pragma unroll
            for (int nt = 0; nt < 4; nt++)
#pragma unroll
                for (int ks = 0; ks < 2; ks++)
                    kn[nt][ks] = *reinterpret_cast<const short8*>(kb2 + (size_t)(nt * 16) * 1024 + ks * 32);
        }
#pragma unroll
        for (int nt = 0; nt < 4; nt++)
#pragma unroll
            for (int ks = 0; ks < 2; ks++)
                vf[nt][ks] = *reinterpret_cast<const short8*>(&Vt[(nt * 16 + l16) * VSTR + ((ks * 32 + quad * 8) ^ (nt << 4))]);
        proc(j == qt);
    }

    // epilogue: one cross-lane sum reduction, normalize, write
#pragma unroll
    for (int r = 0; r < 4; r++) {
        float la = s[r];
#pragma unroll
        for (int msk = 1; msk < 16; msk <<= 1) la += __shfl_xor(la, msk);
        const float inv = 1.0f / la;
        const int rloc = wave * 16 + quad * 4 + r;
        const size_t row = base + (size_t)(qt * 64 + rloc) * 1024;
#pragma unroll
        for (int dt = 0; dt < 4; dt++)
            O[row + dt * 16 + l16] = f2b(o[dt][r] * inv);
    }
}

// ---------------------------------------------------------------------------
extern "C" void kernel_launch(void* const* d_in, const int* in_sizes, int n_in,
                              void* d_out, int out_size, void* d_ws, size_t ws_size,
                              hipStream_t stream) {
    (void)in_sizes; (void)n_in; (void)out_size; (void)ws_size;
    const float* x  = (const float*)d_in[0];
    const float* wq = (const float*)d_in[1];
    const float* wk = (const float*)d_in[2];
    const float* wv = (const float*)d_in[3];
    const float* wo = (const float*)d_in[4];

    const size_t MN = (size_t)4096 * 1024;

    // d_out (16MB): xb (8MB) + wcat (6MB) + rope table (512KB in free tail);
    // all consumed before the final fp32 GEMM overwrites d_out.
    u16* xb   = (u16*)d_out;
    u16* wcat = xb + MN;                    // [3072][1024] = wq|wk|wv rows
    float2* tab = (float2*)(wcat + (size_t)3072 * 1024);
    u16* qbuf = (u16*)d_ws;                 // also attention output
    u16* kbuf = qbuf + MN;
    u16* vbuf = kbuf + MN;
    u16* wob  = vbuf + MN;                  // ws total: 26MB

    cvt_all<<<4096, 256, 0, stream>>>((const float4*)x, (const float4*)wq,
                                      (const float4*)wk, (const float4*)wv,
                                      (const float4*)wo, xb, wcat, wob);
    rope_tab<<<256, 256, 0, stream>>>(tab);
    gemm_tile<4, 1, 24><<<768, 256, 0, stream>>>(xb, wcat, qbuf, kbuf, vbuf, nullptr, tab);
    attn_kernel<<<1024, 256, 0, stream>>>(qbuf, kbuf, vbuf, qbuf);
    gemm_tile<2, 0, 16><<<512, 256, 0, stream>>>(qbuf, wob, nullptr, nullptr, nullptr, (float*)d_out, nullptr);
}

// Round 2
// 266.208 us; speedup vs baseline: 1.0867x; 1.0867x over previous
//
#include <hip/hip_runtime.h>

// MHA forward, B=2, S=2048, D=1024, H=16, Dk=64, causal, RoPE. fp32 I/O.
// Internal bf16 MFMA 16x16x32, fp32 accum.
// R11: QKV epilogue was trig-bound; RoPE cos/sin precomputed into a 2048x32
// float2 table by a tiny kernel; GEMM epilogue does one 8B load instead.
// R12: un-paired q-tiles (1024 blocks) for occupancy, but __launch_bounds__
// (256,4) forced VGPR=64 -> massive scratch spills (WRITE_SIZE 8->99MB),
// attn 72->133us. R13: same un-paired structure, bound relaxed to (256,2)
// (the config that compiled the strictly-larger paired kernel to 116 VGPR,
// spill-free). Actual VGPR <=116 <=128 gives 4 blocks/CU from HW occupancy
// rules without starving the allocator.

typedef unsigned short u16;
typedef __attribute__((ext_vector_type(8))) short short8;   // 8 bf16 = 4 VGPRs
typedef __attribute__((ext_vector_type(4))) float float4v;  // MFMA C/D

typedef const __attribute__((address_space(1))) void GV;    // global
typedef __attribute__((address_space(3))) void LV;          // LDS

#define VSTR 72   // attn Vt/Ps row stride (u16): 144B rows, 2-way read banks
#define QSCL 0.18033688011112042f   // 0.125 * log2(e)

__device__ __forceinline__ u16 f2b(float f) {
    union { float f; unsigned int i; } t; t.f = f;
    unsigned int r = t.i + 0x7fffu + ((t.i >> 16) & 1u);   // RNE
    return (u16)(r >> 16);
}

// ---------------- fused fp32 -> bf16 converter ------------------------------
__global__ __launch_bounds__(256) void cvt_all(
    const float4* __restrict__ x,  const float4* __restrict__ wq,
    const float4* __restrict__ wk, const float4* __restrict__ wv,
    const float4* __restrict__ wo,
    u16* __restrict__ xb, u16* __restrict__ wcat, u16* __restrict__ wob)
{
    const int i = blockIdx.x * 256 + threadIdx.x;
    const float4* s; u16* d; int off;
    if (i < 524288) { s = x; d = xb; off = i; }
    else {
        const int widx = i - 524288;
        const int w = widx >> 17, o = widx & 131071;
        switch (w) {
            case 0:  s = wq; d = wcat;              break;
            case 1:  s = wk; d = wcat + (1 << 20);  break;
            case 2:  s = wv; d = wcat + (2 << 20);  break;
            default: s = wo; d = wob;               break;
        }
        off = o;
    }
    float4 a = s[2 * off], b = s[2 * off + 1];
    u16 t[8] = {f2b(a.x), f2b(a.y), f2b(a.z), f2b(a.w),
                f2b(b.x), f2b(b.y), f2b(b.z), f2b(b.w)};
    reinterpret_cast<int4*>(d)[off] = *reinterpret_cast<int4*>(t);
}

// ---------------- RoPE cos/sin table: tab[pos*32+fi] = {cos, sin} ----------
__global__ __launch_bounds__(256) void rope_tab(float2* __restrict__ tab) {
    const int i = blockIdx.x * 256 + threadIdx.x;   // 0..65535
    const int pos = i >> 5, fi = i & 31;
    const float freq = exp2f((float)fi * -0.4152410118609203f);  // -log2(1e4)/32
    float sn, cs; sincosf((float)pos * freq, &sn, &cs);
    tab[i] = make_float2(cs, sn);
}

// ---------------------------------------------------------------------------
// Y[m][n] = sum_k X[m][k] * W[n][k]; 128(m) x NT*32(n) x 64(k) tiles.
// Staging: global_load_lds width=16. LDS: 64-elem rows, 16B unit u stored at
// phys u^(row&7) (lane-contiguous DMA dest, swizzled ds_read_b128).
// ROPE=1: route cols to Yq/Yk/Yv, RoPE q,k via table, scale q by QSCL.
// XCD swizzle: block g -> xcd=g&7 owns m-strips [xcd*4, xcd*4+4).
// ---------------------------------------------------------------------------
template<int NT, int ROPE, int NBLK>
__global__ __launch_bounds__(256) void gemm_tile(
    const u16* __restrict__ X, const u16* __restrict__ Wb,
    u16* __restrict__ Yq, u16* __restrict__ Yk, u16* __restrict__ Yv,
    float* __restrict__ Yf, const float2* __restrict__ tab)
{
    __shared__ u16 As[128 * 64];
    __shared__ u16 Bs[NT * 32 * 64];

    const int tid  = threadIdx.x;
    const int wave = tid >> 6;
    const int lane = tid & 63;
    const int quad = lane >> 4;
    const int l16  = lane & 15;
    const int wm = (wave >> 1) * 64, wn = (wave & 1) * (NT * 16);
    const int g = blockIdx.x;
    const int rr = g >> 3;
    const int m0 = ((g & 7) * 4 + rr / NBLK) * 128;
    const int n0 = (rr % NBLK) * (NT * 32);
    const int lrow = lane >> 3;                         // 0..7 within 8-row slab
    const int cg8  = (lane & 7) ^ lrow;                 // swizzled global unit

    float4v acc[4][NT];
#pragma unroll
    for (int mt = 0; mt < 4; mt++)
#pragma unroll
        for (int nt = 0; nt < NT; nt++) acc[mt][nt] = (float4v){0.f, 0.f, 0.f, 0.f};

    for (int kb = 0; kb < 1024; kb += 64) {
        __syncthreads();                                 // prev reads done
#pragma unroll
        for (int t = 0; t < 4; t++) {                    // stage A: 4x 1KB/wave
            const int I = wave * 4 + t;
            const u16* gp = X + (size_t)(m0 + I * 8 + lrow) * 1024 + kb + cg8 * 8;
            __builtin_amdgcn_global_load_lds((GV*)gp, (LV*)&As[I * 512], 16, 0, 0);
        }
#pragma unroll
        for (int t = 0; t < NT; t++) {                   // stage B: NTx 1KB/wave
            const int I = wave * NT + t;
            const u16* gp = Wb + (size_t)(n0 + I * 8 + lrow) * 1024 + kb + cg8 * 8;
            __builtin_amdgcn_global_load_lds((GV*)gp, (LV*)&Bs[I * 512], 16, 0, 0);
        }
        __syncthreads();                                 // vmcnt drained here
#pragma unroll
        for (int ks = 0; ks < 2; ks++) {
            const int su = ((ks * 4 + quad) ^ (l16 & 7)) * 8;   // swizzled unit
            short8 af[4], bf[NT];
#pragma unroll
            for (int t = 0; t < 4; t++)
                af[t] = *reinterpret_cast<const short8*>(&As[(wm + t * 16 + l16) * 64 + su]);
#pragma unroll
            for (int t = 0; t < NT; t++)
                bf[t] = *reinterpret_cast<const short8*>(&Bs[(wn + t * 16 + l16) * 64 + su]);
#pragma unroll
            for (int mt = 0; mt < 4; mt++)
#pragma unroll
                for (int nt = 0; nt < NT; nt++)
                    acc[mt][nt] = __builtin_amdgcn_mfma_f32_16x16x32_bf16(af[mt], bf[nt], acc[mt][nt], 0, 0, 0);
        }
    }

    if (ROPE) {
#pragma unroll
        for (int nt = 0; nt < NT; nt++) {
            const int cg = n0 + wn + nt * 16 + l16;      // global col 0..3071
            const int buf = cg >> 10;                    // 0=q 1=k 2=v
            const int c = cg & 1023;
            u16* dst = (buf == 0) ? Yq : ((buf == 1) ? Yk : Yv);
            const bool rp = (buf < 2);
            const float scl = (buf == 0) ? QSCL : 1.0f;
            const int fi = (cg & 63) >> 1;               // pair index in head
#pragma unroll
            for (int mt = 0; mt < 4; mt++)
#pragma unroll
                for (int r = 0; r < 4; r++) {
                    const int row = m0 + wm + mt * 16 + quad * 4 + r;
                    float v = acc[mt][nt][r];
                    if (rp) {
                        const float2 t = tab[((row & 2047) << 5) + fi];
                        const float partner = __shfl_xor(v, 1);
                        v = (l16 & 1) ? fmaf(v, t.x,  partner * t.y)
                                      : fmaf(v, t.x, -partner * t.y);
                    }
                    dst[(size_t)row * 1024 + c] = f2b(v * scl);
                }
        }
    } else {
#pragma unroll
        for (int nt = 0; nt < NT; nt++) {
            const int col = n0 + wn + nt * 16 + l16;
#pragma unroll
            for (int mt = 0; mt < 4; mt++)
#pragma unroll
                for (int r = 0; r < 4; r++) {
                    const int row = m0 + wm + mt * 16 + quad * 4 + r;
                    Yf[(size_t)row * 1024 + col] = acc[mt][nt][r];
                }
        }
    }
}

// ---------------------------------------------------------------------------
// Flash causal attention, ONE 64-row q-tile per block (1024 blocks).
// Unnormalized softmax (q pre-scaled 0.125*log2e -> p = exp2f(s)). K frags
// direct from global, prefetched. V staged coalesced into XOR-swizzled LDS
// transpose. XCD grouping: 32 blocks of one (b,h) share an XCD's L2.
// Complementary (i, 31-i) slot interleave balances per-CU work under
// round-robin dispatch. O aliases Q. Bound (256,2): allocator free (paired
// variant compiled to 116 VGPR spill-free here); actual <=128 -> 4 blk/CU.
// ---------------------------------------------------------------------------
__global__ __launch_bounds__(256, 2) void attn_kernel(
    const u16* Q, const u16* __restrict__ K,
    const u16* __restrict__ V, u16* O)
{
    __shared__ u16 Vt[64 * VSTR];           // Vt[d][s^((d>>4)<<4)]
    __shared__ u16 Ps[4 * 16 * VSTR];

    const int tid  = threadIdx.x;
    const int wave = tid >> 6;
    const int lane = tid & 63;
    const int quad = lane >> 4;
    const int l16  = lane & 15;
    const int g = blockIdx.x;
    const int xcd = g & 7, slot = g >> 3;   // slot 0..127 per XCD
    const int grp = slot >> 5;              // 0..3: (b,h) group on this XCD
    const int i5  = slot & 31;
    const int G = grp * 8 + xcd;            // 0..31 = (b,h) group
    const int qt = (grp & 1) ? i5 : 31 - i5;   // complementary interleave
    const int b = G & 1, h = G >> 1;
    const size_t base = ((size_t)b * 2048) * 1024 + (size_t)h * 64;

    short8 qf[2];
    {
        const size_t ra = base + (size_t)(qt * 64 + wave * 16 + l16) * 1024;
        qf[0] = *reinterpret_cast<const short8*>(Q + ra + quad * 8);
        qf[1] = *reinterpret_cast<const short8*>(Q + ra + 32 + quad * 8);
    }

    float4v o[4];
#pragma unroll
    for (int i = 0; i < 4; i++) o[i] = (float4v){0.f,0.f,0.f,0.f};
    float s[4] = {0.f,0.f,0.f,0.f};

    u16* Pw = Ps + wave * 16 * VSTR;
    const int srow = tid >> 2;             // 0..63 (coalesced: 4 lanes/row)
    const int cb   = (tid & 3) << 4;       // 0,16,32,48
    const int sxw  = srow ^ cb;            // swizzled s ((d>>4)<<4 == cb)

    const u16* Vp = V + base + (size_t)srow * 1024 + cb;
    const u16* kbase = K + base + (size_t)l16 * 1024 + quad * 8;
    int4 vr0 = *reinterpret_cast<const int4*>(Vp);
    int4 vr1 = *reinterpret_cast<const int4*>(Vp + 8);
    short8 kn[4][2], kc[4][2], vf[4][2];
#pragma unroll
    for (int nt = 0; nt < 4; nt++)
#pragma unroll
        for (int ks = 0; ks < 2; ks++)
            kn[nt][ks] = *reinterpret_cast<const short8*>(kbase + (size_t)(nt * 16) * 1024 + ks * 32);

    auto proc = [&](bool diag) {
        float4v sacc[4];
#pragma unroll
        for (int nt = 0; nt < 4; nt++) {
            sacc[nt] = (float4v){0.f, 0.f, 0.f, 0.f};
#pragma unroll
            for (int ks = 0; ks < 2; ks++)
                sacc[nt] = __builtin_amdgcn_mfma_f32_16x16x32_bf16(qf[ks], kc[nt][ks], sacc[nt], 0, 0, 0);
        }
#pragma unroll
        for (int r = 0; r < 4; r++) {
            const int qloc = wave * 16 + quad * 4 + r;
#pragma unroll
            for (int nt = 0; nt < 4; nt++) {
                float sv = sacc[nt][r];                      // log2-domain
                if (diag && (nt * 16 + l16 > qloc)) sv = -1e30f;
                const float p = exp2f(sv);                   // masked -> 0
                s[r] += p;
                Pw[(quad * 4 + r) * VSTR + nt * 16 + l16] = f2b(p);
            }
        }
        __builtin_amdgcn_wave_barrier();   // P write->read is wave-local
#pragma unroll
        for (int ks = 0; ks < 2; ks++) {
            short8 pf = *reinterpret_cast<const short8*>(&Pw[l16 * VSTR + ks * 32 + quad * 8]);
#pragma unroll
            for (int dt = 0; dt < 4; dt++)
                o[dt] = __builtin_amdgcn_mfma_f32_16x16x32_bf16(pf, vf[dt][ks], o[dt], 0, 0, 0);
        }
        __builtin_amdgcn_wave_barrier();
    };

    for (int j = 0; j <= qt; j++) {
        __syncthreads();   // all waves done reading previous Vt
        {
            const u16* a = reinterpret_cast<const u16*>(&vr0);   // V[srow][cb..+7]
            const u16* c = reinterpret_cast<const u16*>(&vr1);   // V[srow][cb+8..+15]
#pragma unroll
            for (int e = 0; e < 8; e++) Vt[(cb + e) * VSTR + sxw] = a[e];
#pragma unroll
            for (int e = 0; e < 8; e++) Vt[(cb + 8 + e) * VSTR + sxw] = c[e];
        }
#pragma unroll
        for (int nt = 0; nt < 4; nt++)
#pragma unroll
            for (int ks = 0; ks < 2; ks++) kc[nt][ks] = kn[nt][ks];
        __syncthreads();
        if (j < qt) {      // prefetch tile j+1; latency hidden by proc
            Vp += 65536;
            vr0 = *reinterpret_cast<const int4*>(Vp);
            vr1 = *reinterpret_cast<const int4*>(Vp + 8);
            const u16* kb2 = kbase + (size_t)(j + 1) * 65536;
#pragma unroll
            for (int nt = 0; nt < 4; nt++)
#pragma unroll
                for (int ks = 0; ks < 2; ks++)
                    kn[nt][ks] = *reinterpret_cast<const short8*>(kb2 + (size_t)(nt * 16) * 1024 + ks * 32);
        }
#pragma unroll
        for (int nt = 0; nt < 4; nt++)
#pragma unroll
            for (int ks = 0; ks < 2; ks++)
                vf[nt][ks] = *reinterpret_cast<const short8*>(&Vt[(nt * 16 + l16) * VSTR + ((ks * 32 + quad * 8) ^ (nt << 4))]);
        proc(j == qt);
    }

    // epilogue: one cross-lane sum reduction, normalize, write
#pragma unroll
    for (int r = 0; r < 4; r++) {
        float la = s[r];
#pragma unroll
        for (int msk = 1; msk < 16; msk <<= 1) la += __shfl_xor(la, msk);
        const float inv = 1.0f / la;
        const int rloc = wave * 16 + quad * 4 + r;
        const size_t row = base + (size_t)(qt * 64 + rloc) * 1024;
#pragma unroll
        for (int dt = 0; dt < 4; dt++)
            O[row + dt * 16 + l16] = f2b(o[dt][r] * inv);
    }
}

// ---------------------------------------------------------------------------
extern "C" void kernel_launch(void* const* d_in, const int* in_sizes, int n_in,
                              void* d_out, int out_size, void* d_ws, size_t ws_size,
                              hipStream_t stream) {
    (void)in_sizes; (void)n_in; (void)out_size; (void)ws_size;
    const float* x  = (const float*)d_in[0];
    const float* wq = (const float*)d_in[1];
    const float* wk = (const float*)d_in[2];
    const float* wv = (const float*)d_in[3];
    const float* wo = (const float*)d_in[4];

    const size_t MN = (size_t)4096 * 1024;

    // d_out (16MB): xb (8MB) + wcat (6MB) + rope table (512KB in free tail);
    // all consumed before the final fp32 GEMM overwrites d_out.
    u16* xb   = (u16*)d_out;
    u16* wcat = xb + MN;                    // [3072][1024] = wq|wk|wv rows
    float2* tab = (float2*)(wcat + (size_t)3072 * 1024);
    u16* qbuf = (u16*)d_ws;                 // also attention output
    u16* kbuf = qbuf + MN;
    u16* vbuf = kbuf + MN;
    u16* wob  = vbuf + MN;                  // ws total: 26MB

    cvt_all<<<4096, 256, 0, stream>>>((const float4*)x, (const float4*)wq,
                                      (const float4*)wk, (const float4*)wv,
                                      (const float4*)wo, xb, wcat, wob);
    rope_tab<<<256, 256, 0, stream>>>(tab);
    gemm_tile<4, 1, 24><<<768, 256, 0, stream>>>(xb, wcat, qbuf, kbuf, vbuf, nullptr, tab);
    attn_kernel<<<1024, 256, 0, stream>>>(qbuf, kbuf, vbuf, qbuf);
    gemm_tile<2, 0, 16><<<512, 256, 0, stream>>>(qbuf, wob, nullptr, nullptr, nullptr, (float*)d_out, nullptr);
}

// Round 3
// 230.826 us; speedup vs baseline: 1.2533x; 1.1533x over previous
//
#include <hip/hip_runtime.h>

// MHA forward, B=2, S=2048, D=1024, H=16, Dk=64, causal, RoPE. fp32 I/O.
// Internal bf16 MFMA 16x16x32, fp32 accum.
// R11: QKV epilogue was trig-bound; RoPE cos/sin precomputed into a 2048x32
// float2 table; GEMM epilogue does one 8B load instead.
// R12/R13 (un-paired 1024-block attn): FALSIFIED. R12's (256,4) bound forced
// VGPR=64 -> 99MB spill traffic. R13 (256,2) was spill-free but 111us vs
// paired 72us: variable-length blocks collapse time-avg residency to ~1
// block/CU under real dispatch (long blocks serialize on the same CUs).
// Equal-work blocks are robust to dispatch order; keep the paired structure.
// R14: R11 chain analysis: 4600cy/iter = 2 procs SERIALIZED through the
// shared Pw LDS slice + wave_barrier (a compiler sched barrier). Fix: per-
// proc Ps slices (LDS 18.4->27.6KB, still 2 blk/CU) + phase-fused dual proc
// QK(A,B) -> sm(A,B) -> barrier -> PV(A,B): A's softmax VALU overlaps B's
// MFMAs, one barrier instead of two.

typedef unsigned short u16;
typedef __attribute__((ext_vector_type(8))) short short8;   // 8 bf16 = 4 VGPRs
typedef __attribute__((ext_vector_type(4))) float float4v;  // MFMA C/D

typedef const __attribute__((address_space(1))) void GV;    // global
typedef __attribute__((address_space(3))) void LV;          // LDS

#define VSTR 72   // attn Vt/Ps row stride (u16): 144B rows, 2-way read banks
#define QSCL 0.18033688011112042f   // 0.125 * log2(e)

__device__ __forceinline__ u16 f2b(float f) {
    union { float f; unsigned int i; } t; t.f = f;
    unsigned int r = t.i + 0x7fffu + ((t.i >> 16) & 1u);   // RNE
    return (u16)(r >> 16);
}

// ---------------- fused fp32 -> bf16 converter ------------------------------
__global__ __launch_bounds__(256) void cvt_all(
    const float4* __restrict__ x,  const float4* __restrict__ wq,
    const float4* __restrict__ wk, const float4* __restrict__ wv,
    const float4* __restrict__ wo,
    u16* __restrict__ xb, u16* __restrict__ wcat, u16* __restrict__ wob)
{
    const int i = blockIdx.x * 256 + threadIdx.x;
    const float4* s; u16* d; int off;
    if (i < 524288) { s = x; d = xb; off = i; }
    else {
        const int widx = i - 524288;
        const int w = widx >> 17, o = widx & 131071;
        switch (w) {
            case 0:  s = wq; d = wcat;              break;
            case 1:  s = wk; d = wcat + (1 << 20);  break;
            case 2:  s = wv; d = wcat + (2 << 20);  break;
            default: s = wo; d = wob;               break;
        }
        off = o;
    }
    float4 a = s[2 * off], b = s[2 * off + 1];
    u16 t[8] = {f2b(a.x), f2b(a.y), f2b(a.z), f2b(a.w),
                f2b(b.x), f2b(b.y), f2b(b.z), f2b(b.w)};
    reinterpret_cast<int4*>(d)[off] = *reinterpret_cast<int4*>(t);
}

// ---------------- RoPE cos/sin table: tab[pos*32+fi] = {cos, sin} ----------
__global__ __launch_bounds__(256) void rope_tab(float2* __restrict__ tab) {
    const int i = blockIdx.x * 256 + threadIdx.x;   // 0..65535
    const int pos = i >> 5, fi = i & 31;
    const float freq = exp2f((float)fi * -0.4152410118609203f);  // -log2(1e4)/32
    float sn, cs; sincosf((float)pos * freq, &sn, &cs);
    tab[i] = make_float2(cs, sn);
}

// ---------------------------------------------------------------------------
// Y[m][n] = sum_k X[m][k] * W[n][k]; 128(m) x NT*32(n) x 64(k) tiles.
// Staging: global_load_lds width=16. LDS: 64-elem rows, 16B unit u stored at
// phys u^(row&7) (lane-contiguous DMA dest, swizzled ds_read_b128).
// ROPE=1: route cols to Yq/Yk/Yv, RoPE q,k via table, scale q by QSCL.
// XCD swizzle: block g -> xcd=g&7 owns m-strips [xcd*4, xcd*4+4).
// ---------------------------------------------------------------------------
template<int NT, int ROPE, int NBLK>
__global__ __launch_bounds__(256) void gemm_tile(
    const u16* __restrict__ X, const u16* __restrict__ Wb,
    u16* __restrict__ Yq, u16* __restrict__ Yk, u16* __restrict__ Yv,
    float* __restrict__ Yf, const float2* __restrict__ tab)
{
    __shared__ u16 As[128 * 64];
    __shared__ u16 Bs[NT * 32 * 64];

    const int tid  = threadIdx.x;
    const int wave = tid >> 6;
    const int lane = tid & 63;
    const int quad = lane >> 4;
    const int l16  = lane & 15;
    const int wm = (wave >> 1) * 64, wn = (wave & 1) * (NT * 16);
    const int g = blockIdx.x;
    const int rr = g >> 3;
    const int m0 = ((g & 7) * 4 + rr / NBLK) * 128;
    const int n0 = (rr % NBLK) * (NT * 32);
    const int lrow = lane >> 3;                         // 0..7 within 8-row slab
    const int cg8  = (lane & 7) ^ lrow;                 // swizzled global unit

    float4v acc[4][NT];
#pragma unroll
    for (int mt = 0; mt < 4; mt++)
#pragma unroll
        for (int nt = 0; nt < NT; nt++) acc[mt][nt] = (float4v){0.f, 0.f, 0.f, 0.f};

    for (int kb = 0; kb < 1024; kb += 64) {
        __syncthreads();                                 // prev reads done
#pragma unroll
        for (int t = 0; t < 4; t++) {                    // stage A: 4x 1KB/wave
            const int I = wave * 4 + t;
            const u16* gp = X + (size_t)(m0 + I * 8 + lrow) * 1024 + kb + cg8 * 8;
            __builtin_amdgcn_global_load_lds((GV*)gp, (LV*)&As[I * 512], 16, 0, 0);
        }
#pragma unroll
        for (int t = 0; t < NT; t++) {                   // stage B: NTx 1KB/wave
            const int I = wave * NT + t;
            const u16* gp = Wb + (size_t)(n0 + I * 8 + lrow) * 1024 + kb + cg8 * 8;
            __builtin_amdgcn_global_load_lds((GV*)gp, (LV*)&Bs[I * 512], 16, 0, 0);
        }
        __syncthreads();                                 // vmcnt drained here
#pragma unroll
        for (int ks = 0; ks < 2; ks++) {
            const int su = ((ks * 4 + quad) ^ (l16 & 7)) * 8;   // swizzled unit
            short8 af[4], bf[NT];
#pragma unroll
            for (int t = 0; t < 4; t++)
                af[t] = *reinterpret_cast<const short8*>(&As[(wm + t * 16 + l16) * 64 + su]);
#pragma unroll
            for (int t = 0; t < NT; t++)
                bf[t] = *reinterpret_cast<const short8*>(&Bs[(wn + t * 16 + l16) * 64 + su]);
#pragma unroll
            for (int mt = 0; mt < 4; mt++)
#pragma unroll
                for (int nt = 0; nt < NT; nt++)
                    acc[mt][nt] = __builtin_amdgcn_mfma_f32_16x16x32_bf16(af[mt], bf[nt], acc[mt][nt], 0, 0, 0);
        }
    }

    if (ROPE) {
#pragma unroll
        for (int nt = 0; nt < NT; nt++) {
            const int cg = n0 + wn + nt * 16 + l16;      // global col 0..3071
            const int buf = cg >> 10;                    // 0=q 1=k 2=v
            const int c = cg & 1023;
            u16* dst = (buf == 0) ? Yq : ((buf == 1) ? Yk : Yv);
            const bool rp = (buf < 2);
            const float scl = (buf == 0) ? QSCL : 1.0f;
            const int fi = (cg & 63) >> 1;               // pair index in head
#pragma unroll
            for (int mt = 0; mt < 4; mt++)
#pragma unroll
                for (int r = 0; r < 4; r++) {
                    const int row = m0 + wm + mt * 16 + quad * 4 + r;
                    float v = acc[mt][nt][r];
                    if (rp) {
                        const float2 t = tab[((row & 2047) << 5) + fi];
                        const float partner = __shfl_xor(v, 1);
                        v = (l16 & 1) ? fmaf(v, t.x,  partner * t.y)
                                      : fmaf(v, t.x, -partner * t.y);
                    }
                    dst[(size_t)row * 1024 + c] = f2b(v * scl);
                }
        }
    } else {
#pragma unroll
        for (int nt = 0; nt < NT; nt++) {
            const int col = n0 + wn + nt * 16 + l16;
#pragma unroll
            for (int mt = 0; mt < 4; mt++)
#pragma unroll
                for (int r = 0; r < 4; r++) {
                    const int row = m0 + wm + mt * 16 + quad * 4 + r;
                    Yf[(size_t)row * 1024 + col] = acc[mt][nt][r];
                }
        }
    }
}

// ---------------------------------------------------------------------------
// Flash causal attention, paired q-tiles (qtA, 31-qtA) -> 512 equal-work
// blocks (robust to dispatch order). Unnormalized softmax (q pre-scaled
// 0.125*log2e -> p = exp2f(s)). K frags direct from global, prefetched.
// V staged coalesced into XOR-swizzled LDS transpose. XCD grouping: 16
// blocks of one (b,h) share an XCD's L2. O aliases Q.
// R14: per-proc Ps slices + phase-fused dual proc so procA/procB ILP-overlap
// (QK A,B -> softmax A,B -> one wave_barrier -> PV A,B) instead of the old
// serial procA; procB through a shared Pw.
// ---------------------------------------------------------------------------
__global__ __launch_bounds__(256, 2) void attn_kernel(
    const u16* Q, const u16* __restrict__ K,
    const u16* __restrict__ V, u16* O)
{
    __shared__ u16 Vt[64 * VSTR];           // Vt[d][s^((d>>4)<<4)]
    __shared__ u16 Ps[8 * 16 * VSTR];       // waves 0-3: procA, 4-7: procB

    const int tid  = threadIdx.x;
    const int wave = tid >> 6;
    const int lane = tid & 63;
    const int quad = lane >> 4;
    const int l16  = lane & 15;
    const int g = blockIdx.x;
    const int xcd = g & 7, slot = g >> 3;
    const int G = (slot >> 4) * 8 + xcd;    // 0..31 = (b,h) group
    const int qtA = slot & 15;              // 0..15
    const int qtB = 31 - qtA;               // 31..16
    const int b = G & 1, h = G >> 1;
    const size_t base = ((size_t)b * 2048) * 1024 + (size_t)h * 64;

    short8 qfA[2], qfB[2];
    {
        const size_t ra = base + (size_t)(qtA * 64 + wave * 16 + l16) * 1024;
        qfA[0] = *reinterpret_cast<const short8*>(Q + ra + quad * 8);
        qfA[1] = *reinterpret_cast<const short8*>(Q + ra + 32 + quad * 8);
        const size_t rb = base + (size_t)(qtB * 64 + wave * 16 + l16) * 1024;
        qfB[0] = *reinterpret_cast<const short8*>(Q + rb + quad * 8);
        qfB[1] = *reinterpret_cast<const short8*>(Q + rb + 32 + quad * 8);
    }

    float4v oA[4], oB[4];
#pragma unroll
    for (int i = 0; i < 4; i++) { oA[i] = (float4v){0.f,0.f,0.f,0.f}; oB[i] = (float4v){0.f,0.f,0.f,0.f}; }
    float sA[4] = {0.f,0.f,0.f,0.f}, sB[4] = {0.f,0.f,0.f,0.f};

    u16* PwA = Ps + wave * 16 * VSTR;
    u16* PwB = Ps + (wave + 4) * 16 * VSTR;
    const int srow = tid >> 2;             // 0..63 (coalesced: 4 lanes/row)
    const int cb   = (tid & 3) << 4;       // 0,16,32,48
    const int sxw  = srow ^ cb;            // swizzled s ((d>>4)<<4 == cb)

    const u16* Vp = V + base + (size_t)srow * 1024 + cb;
    const u16* kbase = K + base + (size_t)l16 * 1024 + quad * 8;
    int4 vr0 = *reinterpret_cast<const int4*>(Vp);
    int4 vr1 = *reinterpret_cast<const int4*>(Vp + 8);
    short8 kn[4][2], kc[4][2], vf[4][2];
#pragma unroll
    for (int nt = 0; nt < 4; nt++)
#pragma unroll
        for (int ks = 0; ks < 2; ks++)
            kn[nt][ks] = *reinterpret_cast<const short8*>(kbase + (size_t)(nt * 16) * 1024 + ks * 32);

    auto qk = [&](const short8 (&qf)[2], float4v (&sacc)[4]) {
#pragma unroll
        for (int nt = 0; nt < 4; nt++) {
            sacc[nt] = (float4v){0.f, 0.f, 0.f, 0.f};
#pragma unroll
            for (int ks = 0; ks < 2; ks++)
                sacc[nt] = __builtin_amdgcn_mfma_f32_16x16x32_bf16(qf[ks], kc[nt][ks], sacc[nt], 0, 0, 0);
        }
    };
    auto sm = [&](const float4v (&sacc)[4], float (&sr)[4], u16* Pw, bool diag) {
#pragma unroll
        for (int r = 0; r < 4; r++) {
            const int qloc = wave * 16 + quad * 4 + r;
#pragma unroll
            for (int nt = 0; nt < 4; nt++) {
                float sv = sacc[nt][r];                      // log2-domain
                if (diag && (nt * 16 + l16 > qloc)) sv = -1e30f;
                const float p = exp2f(sv);                   // masked -> 0
                sr[r] += p;
                Pw[(quad * 4 + r) * VSTR + nt * 16 + l16] = f2b(p);
            }
        }
    };
    auto pv = [&](const u16* Pw, float4v (&oc)[4]) {
#pragma unroll
        for (int ks = 0; ks < 2; ks++) {
            short8 pf = *reinterpret_cast<const short8*>(&Pw[l16 * VSTR + ks * 32 + quad * 8]);
#pragma unroll
            for (int dt = 0; dt < 4; dt++)
                oc[dt] = __builtin_amdgcn_mfma_f32_16x16x32_bf16(pf, vf[dt][ks], oc[dt], 0, 0, 0);
        }
    };

    for (int j = 0; j <= qtB; j++) {
        __syncthreads();   // all waves done reading previous Vt
        {
            const u16* a = reinterpret_cast<const u16*>(&vr0);   // V[srow][cb..+7]
            const u16* c = reinterpret_cast<const u16*>(&vr1);   // V[srow][cb+8..+15]
#pragma unroll
            for (int e = 0; e < 8; e++) Vt[(cb + e) * VSTR + sxw] = a[e];
#pragma unroll
            for (int e = 0; e < 8; e++) Vt[(cb + 8 + e) * VSTR + sxw] = c[e];
        }
#pragma unroll
        for (int nt = 0; nt < 4; nt++)
#pragma unroll
            for (int ks = 0; ks < 2; ks++) kc[nt][ks] = kn[nt][ks];
        __syncthreads();
        if (j < qtB) {     // prefetch tile j+1; latency hidden by procs
            Vp += 65536;
            vr0 = *reinterpret_cast<const int4*>(Vp);
            vr1 = *reinterpret_cast<const int4*>(Vp + 8);
            const u16* kb2 = kbase + (size_t)(j + 1) * 65536;
#pragma unroll
            for (int nt = 0; nt < 4; nt++)
#pragma unroll
                for (int ks = 0; ks < 2; ks++)
                    kn[nt][ks] = *reinterpret_cast<const short8*>(kb2 + (size_t)(nt * 16) * 1024 + ks * 32);
        }
#pragma unroll
        for (int nt = 0; nt < 4; nt++)
#pragma unroll
            for (int ks = 0; ks < 2; ks++)
                vf[nt][ks] = *reinterpret_cast<const short8*>(&Vt[(nt * 16 + l16) * VSTR + ((ks * 32 + quad * 8) ^ (nt << 4))]);

        if (j <= qtA) {    // fused dual proc: A and B phases interleaved
            float4v xA[4], xB[4];
            qk(qfA, xA);
            qk(qfB, xB);
            sm(xA, sA, PwA, j == qtA);
            sm(xB, sB, PwB, false);      // qtB >= 16 > qtA >= j: never diag
            __builtin_amdgcn_wave_barrier();   // P write->read is wave-local
            pv(PwA, oA);
            pv(PwB, oB);
            __builtin_amdgcn_wave_barrier();   // protect Pw reuse next j
        } else {           // tail: only B remains
            float4v xB[4];
            qk(qfB, xB);
            sm(xB, sB, PwB, j == qtB);
            __builtin_amdgcn_wave_barrier();
            pv(PwB, oB);
            __builtin_amdgcn_wave_barrier();
        }
    }

    // epilogue: one cross-lane sum reduction, normalize, write
#pragma unroll
    for (int r = 0; r < 4; r++) {
        float la = sA[r], lb = sB[r];
#pragma unroll
        for (int msk = 1; msk < 16; msk <<= 1) { la += __shfl_xor(la, msk); lb += __shfl_xor(lb, msk); }
        const float invA = 1.0f / la, invB = 1.0f / lb;
        const int rloc = wave * 16 + quad * 4 + r;
        const size_t rowA = base + (size_t)(qtA * 64 + rloc) * 1024;
        const size_t rowB = base + (size_t)(qtB * 64 + rloc) * 1024;
#pragma unroll
        for (int dt = 0; dt < 4; dt++) {
            O[rowA + dt * 16 + l16] = f2b(oA[dt][r] * invA);
            O[rowB + dt * 16 + l16] = f2b(oB[dt][r] * invB);
        }
    }
}

// ---------------------------------------------------------------------------
extern "C" void kernel_launch(void* const* d_in, const int* in_sizes, int n_in,
                              void* d_out, int out_size, void* d_ws, size_t ws_size,
                              hipStream_t stream) {
    (void)in_sizes; (void)n_in; (void)out_size; (void)ws_size;
    const float* x  = (const float*)d_in[0];
    const float* wq = (const float*)d_in[1];
    const float* wk = (const float*)d_in[2];
    const float* wv = (const float*)d_in[3];
    const float* wo = (const float*)d_in[4];

    const size_t MN = (size_t)4096 * 1024;

    // d_out (16MB): xb (8MB) + wcat (6MB) + rope table (512KB in free tail);
    // all consumed before the final fp32 GEMM overwrites d_out.
    u16* xb   = (u16*)d_out;
    u16* wcat = xb + MN;                    // [3072][1024] = wq|wk|wv rows
    float2* tab = (float2*)(wcat + (size_t)3072 * 1024);
    u16* qbuf = (u16*)d_ws;                 // also attention output
    u16* kbuf = qbuf + MN;
    u16* vbuf = kbuf + MN;
    u16* wob  = vbuf + MN;                  // ws total: 26MB

    cvt_all<<<4096, 256, 0, stream>>>((const float4*)x, (const float4*)wq,
                                      (const float4*)wk, (const float4*)wv,
                                      (const float4*)wo, xb, wcat, wob);
    rope_tab<<<256, 256, 0, stream>>>(tab);
    gemm_tile<4, 1, 24><<<768, 256, 0, stream>>>(xb, wcat, qbuf, kbuf, vbuf, nullptr, tab);
    attn_kernel<<<512, 256, 0, stream>>>(qbuf, kbuf, vbuf, qbuf);
    gemm_tile<2, 0, 16><<<512, 256, 0, stream>>>(qbuf, wob, nullptr, nullptr, nullptr, (float*)d_out, nullptr);
}

// Round 5
// 228.036 us; speedup vs baseline: 1.2686x; 1.0122x over previous
//
#include <hip/hip_runtime.h>

// MHA forward, B=2, S=2048, D=1024, H=16, Dk=64, causal, RoPE. fp32 I/O.
// Internal bf16 MFMA 16x16x32, fp32 accum.
// R11: RoPE cos/sin precomputed into a 2048x32 float2 table.
// R12/R13 (un-paired attn): FALSIFIED — forced VGPR cap spilled (R12);
// variable-length blocks collapse residency under real dispatch (R13).
// R14 (phase-fused dual proc): NEUTRAL — counters identical to R11, so
// proc serialization wasn't the limiter; the intra-proc chain is:
// f2b x16 -> ds_write x16 -> barrier -> ds_read_b128 (120cy) -> PV.
// R15: swapped QK^T (mfma(K,Q)) makes q lane-local: P[q=l16][k] lives in
// registers. P->bf16 via v_cvt_pk_bf16_f32 (8 words vs 64 VALU f2b), quad
// exchange via 16 ds_bpermute + 8 selects. P LDS buffer, its barriers and
// the 120cy read latency are deleted (LDS 27.6->9.2KB).
// R16: resubmit of R15 — prior bench died in the container broker (no
// counters, no fail verdict); kernel re-audited (indexing, OOB, ISA) clean.

typedef unsigned short u16;
typedef __attribute__((ext_vector_type(8))) short short8;   // 8 bf16 = 4 VGPRs
typedef __attribute__((ext_vector_type(4))) float float4v;  // MFMA C/D

typedef const __attribute__((address_space(1))) void GV;    // global
typedef __attribute__((address_space(3))) void LV;          // LDS

#define VSTR 72   // attn Vt row stride (u16): 144B rows, 2-way read banks
#define QSCL 0.18033688011112042f   // 0.125 * log2(e)

__device__ __forceinline__ u16 f2b(float f) {
    union { float f; unsigned int i; } t; t.f = f;
    unsigned int r = t.i + 0x7fffu + ((t.i >> 16) & 1u);   // RNE
    return (u16)(r >> 16);
}

// ---------------- fused fp32 -> bf16 converter ------------------------------
__global__ __launch_bounds__(256) void cvt_all(
    const float4* __restrict__ x,  const float4* __restrict__ wq,
    const float4* __restrict__ wk, const float4* __restrict__ wv,
    const float4* __restrict__ wo,
    u16* __restrict__ xb, u16* __restrict__ wcat, u16* __restrict__ wob)
{
    const int i = blockIdx.x * 256 + threadIdx.x;
    const float4* s; u16* d; int off;
    if (i < 524288) { s = x; d = xb; off = i; }
    else {
        const int widx = i - 524288;
        const int w = widx >> 17, o = widx & 131071;
        switch (w) {
            case 0:  s = wq; d = wcat;              break;
            case 1:  s = wk; d = wcat + (1 << 20);  break;
            case 2:  s = wv; d = wcat + (2 << 20);  break;
            default: s = wo; d = wob;               break;
        }
        off = o;
    }
    float4 a = s[2 * off], b = s[2 * off + 1];
    u16 t[8] = {f2b(a.x), f2b(a.y), f2b(a.z), f2b(a.w),
                f2b(b.x), f2b(b.y), f2b(b.z), f2b(b.w)};
    reinterpret_cast<int4*>(d)[off] = *reinterpret_cast<int4*>(t);
}

// ---------------- RoPE cos/sin table: tab[pos*32+fi] = {cos, sin} ----------
__global__ __launch_bounds__(256) void rope_tab(float2* __restrict__ tab) {
    const int i = blockIdx.x * 256 + threadIdx.x;   // 0..65535
    const int pos = i >> 5, fi = i & 31;
    const float freq = exp2f((float)fi * -0.4152410118609203f);  // -log2(1e4)/32
    float sn, cs; sincosf((float)pos * freq, &sn, &cs);
    tab[i] = make_float2(cs, sn);
}

// ---------------------------------------------------------------------------
// Y[m][n] = sum_k X[m][k] * W[n][k]; 128(m) x NT*32(n) x 64(k) tiles.
// Staging: global_load_lds width=16. LDS: 64-elem rows, 16B unit u stored at
// phys u^(row&7) (lane-contiguous DMA dest, swizzled ds_read_b128).
// ROPE=1: route cols to Yq/Yk/Yv, RoPE q,k via table, scale q by QSCL.
// XCD swizzle: block g -> xcd=g&7 owns m-strips [xcd*4, xcd*4+4).
// ---------------------------------------------------------------------------
template<int NT, int ROPE, int NBLK>
__global__ __launch_bounds__(256) void gemm_tile(
    const u16* __restrict__ X, const u16* __restrict__ Wb,
    u16* __restrict__ Yq, u16* __restrict__ Yk, u16* __restrict__ Yv,
    float* __restrict__ Yf, const float2* __restrict__ tab)
{
    __shared__ u16 As[128 * 64];
    __shared__ u16 Bs[NT * 32 * 64];

    const int tid  = threadIdx.x;
    const int wave = tid >> 6;
    const int lane = tid & 63;
    const int quad = lane >> 4;
    const int l16  = lane & 15;
    const int wm = (wave >> 1) * 64, wn = (wave & 1) * (NT * 16);
    const int g = blockIdx.x;
    const int rr = g >> 3;
    const int m0 = ((g & 7) * 4 + rr / NBLK) * 128;
    const int n0 = (rr % NBLK) * (NT * 32);
    const int lrow = lane >> 3;                         // 0..7 within 8-row slab
    const int cg8  = (lane & 7) ^ lrow;                 // swizzled global unit

    float4v acc[4][NT];
#pragma unroll
    for (int mt = 0; mt < 4; mt++)
#pragma unroll
        for (int nt = 0; nt < NT; nt++) acc[mt][nt] = (float4v){0.f, 0.f, 0.f, 0.f};

    for (int kb = 0; kb < 1024; kb += 64) {
        __syncthreads();                                 // prev reads done
#pragma unroll
        for (int t = 0; t < 4; t++) {                    // stage A: 4x 1KB/wave
            const int I = wave * 4 + t;
            const u16* gp = X + (size_t)(m0 + I * 8 + lrow) * 1024 + kb + cg8 * 8;
            __builtin_amdgcn_global_load_lds((GV*)gp, (LV*)&As[I * 512], 16, 0, 0);
        }
#pragma unroll
        for (int t = 0; t < NT; t++) {                   // stage B: NTx 1KB/wave
            const int I = wave * NT + t;
            const u16* gp = Wb + (size_t)(n0 + I * 8 + lrow) * 1024 + kb + cg8 * 8;
            __builtin_amdgcn_global_load_lds((GV*)gp, (LV*)&Bs[I * 512], 16, 0, 0);
        }
        __syncthreads();                                 // vmcnt drained here
#pragma unroll
        for (int ks = 0; ks < 2; ks++) {
            const int su = ((ks * 4 + quad) ^ (l16 & 7)) * 8;   // swizzled unit
            short8 af[4], bf[NT];
#pragma unroll
            for (int t = 0; t < 4; t++)
                af[t] = *reinterpret_cast<const short8*>(&As[(wm + t * 16 + l16) * 64 + su]);
#pragma unroll
            for (int t = 0; t < NT; t++)
                bf[t] = *reinterpret_cast<const short8*>(&Bs[(wn + t * 16 + l16) * 64 + su]);
#pragma unroll
            for (int mt = 0; mt < 4; mt++)
#pragma unroll
                for (int nt = 0; nt < NT; nt++)
                    acc[mt][nt] = __builtin_amdgcn_mfma_f32_16x16x32_bf16(af[mt], bf[nt], acc[mt][nt], 0, 0, 0);
        }
    }

    if (ROPE) {
#pragma unroll
        for (int nt = 0; nt < NT; nt++) {
            const int cg = n0 + wn + nt * 16 + l16;      // global col 0..3071
            const int buf = cg >> 10;                    // 0=q 1=k 2=v
            const int c = cg & 1023;
            u16* dst = (buf == 0) ? Yq : ((buf == 1) ? Yk : Yv);
            const bool rp = (buf < 2);
            const float scl = (buf == 0) ? QSCL : 1.0f;
            const int fi = (cg & 63) >> 1;               // pair index in head
#pragma unroll
            for (int mt = 0; mt < 4; mt++)
#pragma unroll
                for (int r = 0; r < 4; r++) {
                    const int row = m0 + wm + mt * 16 + quad * 4 + r;
                    float v = acc[mt][nt][r];
                    if (rp) {
                        const float2 t = tab[((row & 2047) << 5) + fi];
                        const float partner = __shfl_xor(v, 1);
                        v = (l16 & 1) ? fmaf(v, t.x,  partner * t.y)
                                      : fmaf(v, t.x, -partner * t.y);
                    }
                    dst[(size_t)row * 1024 + c] = f2b(v * scl);
                }
        }
    } else {
#pragma unroll
        for (int nt = 0; nt < NT; nt++) {
            const int col = n0 + wn + nt * 16 + l16;
#pragma unroll
            for (int mt = 0; mt < 4; mt++)
#pragma unroll
                for (int r = 0; r < 4; r++) {
                    const int row = m0 + wm + mt * 16 + quad * 4 + r;
                    Yf[(size_t)row * 1024 + col] = acc[mt][nt][r];
                }
        }
    }
}

// ---------------------------------------------------------------------------
// Flash causal attention, paired q-tiles (qtA, 31-qtA) -> 512 equal-work
// blocks. Unnormalized softmax (q pre-scaled 0.125*log2e -> p = exp2f(s)).
// K frags direct from global, prefetched. V staged coalesced into
// XOR-swizzled LDS transpose. XCD grouping: 16 blocks of one (b,h) share an
// XCD's L2. O aliases Q.
// R15: SWAPPED QK^T -> lane holds S[q=wave*16+l16][k=nt*16+quad*4+r]; P is
// packed in-register (v_cvt_pk_bf16_f32) and redistributed to the PV
// A-fragment with 16 ds_bpermute + 8 selects. No P LDS, no barriers, no
// 120cy P-read latency in the chain. Row-sum s is one scalar/lane (q=l16),
// quad-reduced + shfl-redistributed in the epilogue.
// ---------------------------------------------------------------------------
__global__ __launch_bounds__(256, 2) void attn_kernel(
    const u16* Q, const u16* __restrict__ K,
    const u16* __restrict__ V, u16* O)
{
    __shared__ u16 Vt[64 * VSTR];           // Vt[d][s^((d>>4)<<4)]

    const int tid  = threadIdx.x;
    const int wave = tid >> 6;
    const int lane = tid & 63;
    const int quad = lane >> 4;
    const int l16  = lane & 15;
    const int g = blockIdx.x;
    const int xcd = g & 7, slot = g >> 3;
    const int G = (slot >> 4) * 8 + xcd;    // 0..31 = (b,h) group
    const int qtA = slot & 15;              // 0..15
    const int qtB = 31 - qtA;               // 31..16
    const int b = G & 1, h = G >> 1;
    const size_t base = ((size_t)b * 2048) * 1024 + (size_t)h * 64;

    short8 qfA[2], qfB[2];
    {
        const size_t ra = base + (size_t)(qtA * 64 + wave * 16 + l16) * 1024;
        qfA[0] = *reinterpret_cast<const short8*>(Q + ra + quad * 8);
        qfA[1] = *reinterpret_cast<const short8*>(Q + ra + 32 + quad * 8);
        const size_t rb = base + (size_t)(qtB * 64 + wave * 16 + l16) * 1024;
        qfB[0] = *reinterpret_cast<const short8*>(Q + rb + quad * 8);
        qfB[1] = *reinterpret_cast<const short8*>(Q + rb + 32 + quad * 8);
    }

    float4v oA[4], oB[4];
#pragma unroll
    for (int i = 0; i < 4; i++) { oA[i] = (float4v){0.f,0.f,0.f,0.f}; oB[i] = (float4v){0.f,0.f,0.f,0.f}; }
    float sA = 0.f, sB = 0.f;               // row-sum partial for q = wave*16+l16

    const int srow = tid >> 2;             // 0..63 (coalesced: 4 lanes/row)
    const int cb   = (tid & 3) << 4;       // 0,16,32,48
    const int sxw  = srow ^ cb;            // swizzled s ((d>>4)<<4 == cb)

    const u16* Vp = V + base + (size_t)srow * 1024 + cb;
    const u16* kbase = K + base + (size_t)l16 * 1024 + quad * 8;
    int4 vr0 = *reinterpret_cast<const int4*>(Vp);
    int4 vr1 = *reinterpret_cast<const int4*>(Vp + 8);
    short8 kn[4][2], kc[4][2], vf[4][2];
#pragma unroll
    for (int nt = 0; nt < 4; nt++)
#pragma unroll
        for (int ks = 0; ks < 2; ks++)
            kn[nt][ks] = *reinterpret_cast<const short8*>(kbase + (size_t)(nt * 16) * 1024 + ks * 32);

    // bpermute byte-addrs: src lane = ((quad&1)*2 + (j>>1))*16 + l16
    const int bpa0 = (((quad & 1) * 2) * 16 + l16) * 4;
    const int bpa1 = bpa0 + 64;
    const bool hiq = quad >= 2;            // selects w[2ks+1] half
    const int qloc = wave * 16 + l16;      // this lane's q within the 64-tile

    // SWAPPED QK: sacc[nt][r] = S[q = wave*16+l16][k = nt*16+quad*4+r]
    auto qk = [&](const short8 (&qf)[2], float4v (&sacc)[4]) {
#pragma unroll
        for (int nt = 0; nt < 4; nt++) {
            sacc[nt] = (float4v){0.f, 0.f, 0.f, 0.f};
#pragma unroll
            for (int ks = 0; ks < 2; ks++)
                sacc[nt] = __builtin_amdgcn_mfma_f32_16x16x32_bf16(kc[nt][ks], qf[ks], sacc[nt], 0, 0, 0);
        }
    };
    // softmax + pack + quad exchange -> PV A-frags pa[ks] (k = ks*32+quad*8+e)
    auto smx = [&](const float4v (&sacc)[4], float &sr, short8 (&pa)[2], bool diag) {
        unsigned int w[4][2];
#pragma unroll
        for (int nt = 0; nt < 4; nt++) {
            float p[4];
#pragma unroll
            for (int r = 0; r < 4; r++) {
                float sv = sacc[nt][r];                      // log2-domain
                if (diag && (nt * 16 + quad * 4 + r > qloc)) sv = -1e30f;
                p[r] = exp2f(sv);                            // masked -> 0
                sr += p[r];
            }
            asm("v_cvt_pk_bf16_f32 %0, %1, %2" : "=v"(w[nt][0]) : "v"(p[0]), "v"(p[1]));
            asm("v_cvt_pk_bf16_f32 %0, %1, %2" : "=v"(w[nt][1]) : "v"(p[2]), "v"(p[3]));
        }
#pragma unroll
        for (int ks = 0; ks < 2; ks++) {
            unsigned int pw[4];
#pragma unroll
            for (int j = 0; j < 4; j++) {
                const int addr = (j >> 1) ? bpa1 : bpa0;
                const int rp = j & 1;
                int lo_ = __builtin_amdgcn_ds_bpermute(addr, (int)w[2 * ks][rp]);
                int hi_ = __builtin_amdgcn_ds_bpermute(addr, (int)w[2 * ks + 1][rp]);
                pw[j] = (unsigned int)(hiq ? hi_ : lo_);
            }
            union { unsigned int u[4]; short8 s; } t;
            t.u[0] = pw[0]; t.u[1] = pw[1]; t.u[2] = pw[2]; t.u[3] = pw[3];
            pa[ks] = t.s;
        }
    };
    auto pv = [&](const short8 (&pa)[2], float4v (&oc)[4]) {
#pragma unroll
        for (int ks = 0; ks < 2; ks++)
#pragma unroll
            for (int dt = 0; dt < 4; dt++)
                oc[dt] = __builtin_amdgcn_mfma_f32_16x16x32_bf16(pa[ks], vf[dt][ks], oc[dt], 0, 0, 0);
    };

    for (int j = 0; j <= qtB; j++) {
        __syncthreads();   // all waves done reading previous Vt
        {
            const u16* a = reinterpret_cast<const u16*>(&vr0);   // V[srow][cb..+7]
            const u16* c = reinterpret_cast<const u16*>(&vr1);   // V[srow][cb+8..+15]
#pragma unroll
            for (int e = 0; e < 8; e++) Vt[(cb + e) * VSTR + sxw] = a[e];
#pragma unroll
            for (int e = 0; e < 8; e++) Vt[(cb + 8 + e) * VSTR + sxw] = c[e];
        }
#pragma unroll
        for (int nt = 0; nt < 4; nt++)
#pragma unroll
            for (int ks = 0; ks < 2; ks++) kc[nt][ks] = kn[nt][ks];
        __syncthreads();
        if (j < qtB) {     // prefetch tile j+1; latency hidden by procs
            Vp += 65536;
            vr0 = *reinterpret_cast<const int4*>(Vp);
            vr1 = *reinterpret_cast<const int4*>(Vp + 8);
            const u16* kb2 = kbase + (size_t)(j + 1) * 65536;
#pragma unroll
            for (int nt = 0; nt < 4; nt++)
#pragma unroll
                for (int ks = 0; ks < 2; ks++)
                    kn[nt][ks] = *reinterpret_cast<const short8*>(kb2 + (size_t)(nt * 16) * 1024 + ks * 32);
        }
#pragma unroll
        for (int nt = 0; nt < 4; nt++)
#pragma unroll
            for (int ks = 0; ks < 2; ks++)
                vf[nt][ks] = *reinterpret_cast<const short8*>(&Vt[(nt * 16 + l16) * VSTR + ((ks * 32 + quad * 8) ^ (nt << 4))]);

        if (j <= qtA) {    // dual proc
            float4v xA[4], xB[4];
            qk(qfA, xA);
            qk(qfB, xB);
            short8 paA[2], paB[2];
            smx(xA, sA, paA, j == qtA);
            smx(xB, sB, paB, false);     // qtB >= 16 > qtA >= j: never diag
            pv(paA, oA);
            pv(paB, oB);
        } else {           // tail: only B remains
            float4v xB[4];
            qk(qfB, xB);
            short8 paB[2];
            smx(xB, sB, paB, j == qtB);
            pv(paB, oB);
        }
    }

    // epilogue: quad-reduce row sums, redistribute via shfl, normalize, write
    float tA = sA, tB = sB;
    tA += __shfl_xor(tA, 16); tA += __shfl_xor(tA, 32);
    tB += __shfl_xor(tB, 16); tB += __shfl_xor(tB, 32);
#pragma unroll
    for (int r = 0; r < 4; r++) {
        const int rl = quad * 4 + r;                 // q-local of o[.][r]
        const float invA = 1.0f / __shfl(tA, rl);    // lane rl holds q=wave*16+rl
        const float invB = 1.0f / __shfl(tB, rl);
        const size_t rowA = base + (size_t)(qtA * 64 + wave * 16 + rl) * 1024;
        const size_t rowB = base + (size_t)(qtB * 64 + wave * 16 + rl) * 1024;
#pragma unroll
        for (int dt = 0; dt < 4; dt++) {
            O[rowA + dt * 16 + l16] = f2b(oA[dt][r] * invA);
            O[rowB + dt * 16 + l16] = f2b(oB[dt][r] * invB);
        }
    }
}

// ---------------------------------------------------------------------------
extern "C" void kernel_launch(void* const* d_in, const int* in_sizes, int n_in,
                              void* d_out, int out_size, void* d_ws, size_t ws_size,
                              hipStream_t stream) {
    (void)in_sizes; (void)n_in; (void)out_size; (void)ws_size;
    const float* x  = (const float*)d_in[0];
    const float* wq = (const float*)d_in[1];
    const float* wk = (const float*)d_in[2];
    const float* wv = (const float*)d_in[3];
    const float* wo = (const float*)d_in[4];

    const size_t MN = (size_t)4096 * 1024;

    // d_out (16MB): xb (8MB) + wcat (6MB) + rope table (512KB in free tail);
    // all consumed before the final fp32 GEMM overwrites d_out.
    u16* xb   = (u16*)d_out;
    u16* wcat = xb + MN;                    // [3072][1024] = wq|wk|wv rows
    float2* tab = (float2*)(wcat + (size_t)3072 * 1024);
    u16* qbuf = (u16*)d_ws;                 // also attention output
    u16* kbuf = qbuf + MN;
    u16* vbuf = kbuf + MN;
    u16* wob  = vbuf + MN;                  // ws total: 26MB

    cvt_all<<<4096, 256, 0, stream>>>((const float4*)x, (const float4*)wq,
                                      (const float4*)wk, (const float4*)wv,
                                      (const float4*)wo, xb, wcat, wob);
    rope_tab<<<256, 256, 0, stream>>>(tab);
    gemm_tile<4, 1, 24><<<768, 256, 0, stream>>>(xb, wcat, qbuf, kbuf, vbuf, nullptr, tab);
    attn_kernel<<<512, 256, 0, stream>>>(qbuf, kbuf, vbuf, qbuf);
    gemm_tile<2, 0, 16><<<512, 256, 0, stream>>>(qbuf, wob, nullptr, nullptr, nullptr, (float*)d_out, nullptr);
}